// Round 12
// baseline (52.045 us; speedup 1.0000x reference)
//
#include <hip/hip_runtime.h>
#include <stdint.h>

typedef __bf16 bf16;
typedef bf16 bf16x8 __attribute__((ext_vector_type(8)));
typedef float f32x4 __attribute__((ext_vector_type(4)));
typedef float f32x16 __attribute__((ext_vector_type(16)));
typedef uint32_t u32;
typedef uint16_t u16;
typedef u32 u32x4 __attribute__((ext_vector_type(4)));

#define BATCH 4
#define NSEQ  4096
#define DHEAD 128
#define GROUPS 4                  // kv-split groups = waves per block
#define KB    32
#define KVSPAN (NSEQ/GROUPS)      // 1024
#define NITER  (KVSPAN/KB)        // 32
#define NKT    (NSEQ/KB)          // 128 packed tiles per batch
#define TILE_B 8192               // bytes per packed tile (Kp and Vp alike)
#define LOG2E 1.44269504088896340736f
#define OROW  136                 // epilogue Obuf row stride (floats)
#define PSEL  0x07060302u         // v_perm selector: [lo.b2, lo.b3, hi.b2, hi.b3]

__device__ __forceinline__ u16 f2bf(float f) {
    u32 u = __builtin_bit_cast(u32, f);
    u += 0x7fff + ((u >> 16) & 1);   // RNE
    return (u16)(u >> 16);
}

// ---------------- prep: fp32 x -> MFMA-fragment-packed bf16 Kp / Vp ----------------
// Kp[kt][dc][hh][r][i] = x[kt*32+r][dc*16+hh*8+i]          (K/Q fragment order)
// Vp[kt][s][db][hh][r][i] = x[kt*32+s*16+hh*8+i][db*32+r]  (V^T fragment order)
__global__ __launch_bounds__(256) void prep_kernel(const float* __restrict__ x,
                                                   char* __restrict__ Kp,
                                                   char* __restrict__ Vp) {
    __shared__ u16 lds[32][136];
    int bid = blockIdx.x;            // 512 blocks = b(4) x kt(128)
    int b = bid >> 7, kt = bid & 127;
    int t = threadIdx.x;
    const float* xt = x + ((size_t)b * NSEQ + kt * 32) * DHEAD;
    #pragma unroll
    for (int j = 0; j < 16; j++) {
        int idx = t + j * 256;
        int r = idx >> 7, c = idx & 127;
        lds[r][c] = f2bf(xt[r * DHEAD + c]);
    }
    __syncthreads();
    char* kout = Kp + (size_t)(b * NKT + kt) * TILE_B;
    char* vout = Vp + (size_t)(b * NKT + kt) * TILE_B;
    #pragma unroll
    for (int j = 0; j < 2; j++) {
        int slot = t + j * 256;      // 512 slots x 16B = 8KB each for K and V
        {   // K slot
            int dc = slot >> 6, hh = (slot >> 5) & 1, r = slot & 31;
            bf16x8 v = *(const bf16x8*)(const void*)(&lds[r][dc * 16 + hh * 8]);
            *(bf16x8*)(void*)(kout + slot * 16) = v;
        }
        {   // V slot (transpose gather from LDS)
            int s = slot >> 8, db = (slot >> 6) & 3, hh = (slot >> 5) & 1, r = slot & 31;
            u16 tmp[8];
            #pragma unroll
            for (int i = 0; i < 8; i++) tmp[i] = lds[s * 16 + hh * 8 + i][db * 32 + r];
            *(bf16x8*)(void*)(vout + slot * 16) = *(const bf16x8*)(const void*)tmp;
        }
    }
}

// ---------------- flash attention: 32 q-rows/wave, 2 waves/SIMD ----------------
// 512 blocks (2/CU) x 4 waves; each wave is one kv-group sweeping 1024 kv rows for the
// block's 32 q-rows. Fixed-C softmax (C = diag score), P->bf16 via v_perm trunc-pack,
// single QK accumulate chain, K register-double-buffered, V loaded at tile top
// (covered by QK+softmax latency). 2 waves/SIMD fill dependency stalls via TLP.
__device__ __forceinline__ void load_k(bf16x8 (&k)[8], const char* p) {
    #pragma unroll
    for (int dc = 0; dc < 8; dc++)
        k[dc] = *(const bf16x8*)(const void*)(p + dc * 1024);
}

__device__ __forceinline__ void load_v(bf16x8 (&v)[8], const char* p) {
    #pragma unroll
    for (int db = 0; db < 4; db++) {
        v[2*db]   = *(const bf16x8*)(const void*)(p + db * 1024);          // s=0
        v[2*db+1] = *(const bf16x8*)(const void*)(p + 4096 + db * 1024);   // s=1
    }
}

__device__ __forceinline__ u32 packbf(float lo, float hi) {
    return __builtin_amdgcn_perm(__builtin_bit_cast(u32, hi),
                                 __builtin_bit_cast(u32, lo), PSEL);
}

__device__ __forceinline__ void attn_tile(const bf16x8 (&kf)[8], const bf16x8 (&vf)[8],
                                          const bf16x8 (&qf)[8], f32x16 (&acc)[4],
                                          float diagL, float& lsum) {
    f32x16 zz = {0.f,0.f,0.f,0.f,0.f,0.f,0.f,0.f,0.f,0.f,0.f,0.f,0.f,0.f,0.f,0.f};
    // QK^T: S^T[kv][q], single accumulate chain (full-rate pipelined)
    f32x16 s = zz;
    #pragma unroll
    for (int dc = 0; dc < 8; dc++)
        s = __builtin_amdgcn_mfma_f32_32x32x16_bf16(kf[dc], qf[dc], s, 0, 0, 0);

    // fixed-shift softmax weights: p = 2^(s*log2e - diagL); no max tracking
    float p[16];
    #pragma unroll
    for (int i = 0; i < 16; i++)
        p[i] = __builtin_amdgcn_exp2f(s[i] * LOG2E - diagL);
    float ss[8];
    #pragma unroll
    for (int i = 0; i < 8; i++) ss[i] = p[i] + p[i + 8];
    #pragma unroll
    for (int i = 0; i < 4; i++) ss[i] += ss[i + 4];
    lsum += (ss[0] + ss[1]) + (ss[2] + ss[3]);

    // P -> bf16 pairs via v_perm trunc-pack -> permlane32_swap -> PV B-fragments
    u32 c01   = packbf(p[0],  p[1]);
    u32 c23   = packbf(p[2],  p[3]);
    u32 c89   = packbf(p[4],  p[5]);
    u32 c1011 = packbf(p[6],  p[7]);
    u32 cA    = packbf(p[8],  p[9]);
    u32 cB    = packbf(p[10], p[11]);
    u32 cC    = packbf(p[12], p[13]);
    u32 cD    = packbf(p[14], p[15]);
    auto sA = __builtin_amdgcn_permlane32_swap(c01, c89,   false, false);
    auto sB = __builtin_amdgcn_permlane32_swap(c23, c1011, false, false);
    auto sC = __builtin_amdgcn_permlane32_swap(cA, cC,     false, false);
    auto sD = __builtin_amdgcn_permlane32_swap(cB, cD,     false, false);
    bf16x8 pb0 = __builtin_bit_cast(bf16x8, (u32x4){sA[0], sB[0], sA[1], sB[1]});
    bf16x8 pb1 = __builtin_bit_cast(bf16x8, (u32x4){sC[0], sD[0], sC[1], sD[1]});

    // PV: out^T += V^T . P^T, 4 d-blocks x 2 k-steps
    #pragma unroll
    for (int db = 0; db < 4; db++) {
        acc[db] = __builtin_amdgcn_mfma_f32_32x32x16_bf16(vf[2*db],     pb0, acc[db], 0, 0, 0);
        acc[db] = __builtin_amdgcn_mfma_f32_32x32x16_bf16(vf[2*db + 1], pb1, acc[db], 0, 0, 0);
    }
}

__global__ __launch_bounds__(256, 2) void attn_kernel(const char* __restrict__ Kp,
                                                      const char* __restrict__ Vp,
                                                      float* __restrict__ out) {
    __shared__ float Obuf[32 * OROW];          // 17.4 KB epilogue combine buffer
    __shared__ float Lx[GROUPS][32];

    int bid = blockIdx.x;            // 512 blocks, 2/CU (8 waves/CU = 2/SIMD)
    int xcd = bid & 7, pos = bid >> 3;
    int b    = xcd >> 1;             // 2 XCDs per batch -> batch (2MB packed) L2-resident
    int qt   = pos + ((xcd & 1) << 6);   // q-tile (32 rows) within batch, 0..127

    int t = threadIdx.x;
    int w = t >> 6, l = t & 63;
    int grp = w;                     // each wave is one kv-group
    int r  = l & 31;                 // lane row (m/n index)
    int hh = l >> 5;                 // k-half

    // per-lane packed bases: fragment load = base + kt*8192 + dc*1024 (+ s*4096)
    const char* Kpb = Kp + (size_t)b * NKT * TILE_B + (size_t)l * 16;
    const char* Vpb = Vp + (size_t)b * NKT * TILE_B + (size_t)l * 16;

    // Q B-fragments (from Kp, identical fragment layout), tile qt
    bf16x8 qf[8];
    load_k(qf, Kpb + (size_t)qt * TILE_B);

    // diag shift C = ||x_q||^2 (own half + cross-half add)
    float dsq = 0.f;
    #pragma unroll
    for (int dc = 0; dc < 8; dc++) {
        #pragma unroll
        for (int i = 0; i < 8; i++) {
            float v = (float)qf[dc][i];
            dsq += v * v;
        }
    }
    dsq += __shfl_xor(dsq, 32);
    float diagL = dsq * LOG2E;

    f32x16 zz = {0.f,0.f,0.f,0.f,0.f,0.f,0.f,0.f,0.f,0.f,0.f,0.f,0.f,0.f,0.f,0.f};
    f32x16 acc[4];                   // out^T: d = db*32+(reg&3)+8*(reg>>2)+4*hh, q = r
    #pragma unroll
    for (int i = 0; i < 4; i++) acc[i] = zz;
    float lsum = 0.f;

    int kt0 = grp * NITER;           // this group's 32 packed tiles
    bf16x8 kA[8], kB[8], vv[8];
    load_k(kA, Kpb + (size_t)kt0 * TILE_B);
    for (int it = 0; it < NITER; it += 2) {
        size_t ktb = (size_t)(kt0 + it) * TILE_B;
        load_v(vv, Vpb + ktb);                                // V for tile it (covered by QK)
        load_k(kB, Kpb + ktb + TILE_B);                       // prefetch K tile it+1
        attn_tile(kA, vv, qf, acc, diagL, lsum);
        load_v(vv, Vpb + ktb + TILE_B);                       // V for tile it+1
        if (it + 2 < NITER)
            load_k(kA, Kpb + ktb + 2 * TILE_B);               // prefetch K tile it+2
        attn_tile(kB, vv, qf, acc, diagL, lsum);
    }

    // ---- combine 4 kv-groups (shared shift per row -> plain sums) ----
    lsum += __shfl_xor(lsum, 32);
    if (l < 32) Lx[grp][r] = lsum;
    __syncthreads();

    #pragma unroll
    for (int j = 0; j < GROUPS; j++) {
        if (grp == j) {
            #pragma unroll
            for (int db = 0; db < 4; db++) {
                #pragma unroll
                for (int rq = 0; rq < 4; rq++) {
                    int d0 = db * 32 + rq * 8 + hh * 4;
                    float* dst = Obuf + r * OROW + d0;
                    f32x4 v = { acc[db][rq*4+0], acc[db][rq*4+1], acc[db][rq*4+2], acc[db][rq*4+3] };
                    if (j > 0) v += *(const f32x4*)(const void*)dst;
                    *(f32x4*)(void*)dst = v;
                }
            }
        }
        __syncthreads();
    }

    // coalesced final store: thread t -> row q2 = t>>3, 16 floats at (t&7)*16
    int q2 = t >> 3;
    float lt = Lx[0][q2] + Lx[1][q2] + Lx[2][q2] + Lx[3][q2];
    float inv = 1.0f / lt;
    const float* srow = Obuf + q2 * OROW + (t & 7) * 16;
    float* orow = out + ((size_t)b * NSEQ + (size_t)qt * 32 + q2) * DHEAD + (t & 7) * 16;
    #pragma unroll
    for (int k = 0; k < 4; k++) {
        f32x4 v = *(const f32x4*)(const void*)(srow + k * 4);
        v *= inv;
        *(f32x4*)(void*)(orow + k * 4) = v;
    }
}

extern "C" void kernel_launch(void* const* d_in, const int* in_sizes, int n_in,
                              void* d_out, int out_size, void* d_ws, size_t ws_size,
                              hipStream_t stream) {
    (void)in_sizes; (void)n_in; (void)out_size; (void)ws_size;
    const float* x = (const float*)d_in[0];
    float* out = (float*)d_out;
    char* Kp = (char*)d_ws;                                    // 4 MB packed K/Q fragments
    char* Vp = Kp + (size_t)BATCH * NKT * TILE_B;              // 4 MB packed V^T fragments
    prep_kernel<<<BATCH * NKT, 256, 0, stream>>>(x, Kp, Vp);
    attn_kernel<<<BATCH * NKT, 256, 0, stream>>>(Kp, Vp, out);
}

// Round 13
// 49.309 us; speedup vs baseline: 1.0555x; 1.0555x over previous
//
#include <hip/hip_runtime.h>
#include <stdint.h>

typedef __bf16 bf16;
typedef bf16 bf16x8 __attribute__((ext_vector_type(8)));
typedef float f32x4 __attribute__((ext_vector_type(4)));
typedef float f32x16 __attribute__((ext_vector_type(16)));
typedef uint32_t u32;
typedef uint16_t u16;
typedef int64_t i64;
typedef u32 u32x4 __attribute__((ext_vector_type(4)));

#define BATCH 4
#define NSEQ  4096
#define DHEAD 128
#define GROUPS 4                  // kv-split groups = waves per block
#define KB    32
#define KVSPAN (NSEQ/GROUPS)      // 1024
#define NITER  (KVSPAN/KB)        // 32
#define NKT    (NSEQ/KB)          // 128 tiles per batch
#define KT8_B  4096               // fp8 K tile bytes
#define VT_B   8192               // bf16 V^T tile bytes
#define LOG2E 1.44269504088896340736f
#define OROW  136                 // epilogue Obuf row stride (floats)

__device__ __forceinline__ u16 f2bf(float f) {
    u32 u = __builtin_bit_cast(u32, f);
    u += 0x7fff + ((u >> 16) & 1);   // RNE
    return (u16)(u >> 16);
}

// f32 -> OCP e4m3fn, RNE (inputs bounded ~|x|<6, so no clamp path in practice)
__device__ __forceinline__ u32 f2fp8(float f) {
    u32 u = __builtin_bit_cast(u32, f);
    u32 sgn = (u >> 24) & 0x80;
    float af = fabsf(f);
    if (af < 0x1.0p-6f) {                      // denorm: steps of 2^-9 (m=8 -> 0x08 = 2^-6)
        u32 m = (u32)rintf(af * 512.0f);
        return sgn | m;
    }
    u32 au = u & 0x7FFFFFFF;
    au += 0x7FFFF + ((au >> 20) & 1);          // RNE at 3-bit mantissa
    u32 e = au >> 23;
    if (e > 135) { e = 135; au = (135u << 23) | (6u << 20); }   // clamp 448
    u32 m3 = (au >> 20) & 7;
    return sgn | ((e - 120) << 3) | m3;
}

// |e4m3fn| -> f32 (sign dropped; used only for squaring)
__device__ __forceinline__ float dfp8(u32 c) {
    u32 a = c & 0x7F;
    u32 e = a >> 3, m = a & 7;
    float norm = __builtin_bit_cast(float, ((e + 120) << 23) | (m << 20));
    float den  = (float)m * 0x1.0p-9f;
    return e ? norm : den;
}

// ---------------- prep: fp32 x -> fp8-packed Kp8 (K/Q fragments) + bf16 Vp ----------------
// Kp8[kt]: offset dcp*1024 + (hh*32+r)*16; 16B = fp8 x[kt*32+r][dcp*32 + b8*16 + hh*8 + i]
//          for b8=0 (low 8B), b8=1 (high 8B)  -> one dwordx4 feeds two K=16 fp8 MFMA operands
// Vp[kt][s][db][hh][r][i] = bf16 x[kt*32+s*16+hh*8+i][db*32+r]   (V^T fragment order)
__global__ __launch_bounds__(256) void prep_kernel(const float* __restrict__ x,
                                                   char* __restrict__ Kp8,
                                                   char* __restrict__ Vp) {
    __shared__ float lds[32][132];
    int bid = blockIdx.x;            // 512 blocks = b(4) x kt(128)
    int b = bid >> 7, kt = bid & 127;
    int t = threadIdx.x;
    const float* xt = x + ((size_t)b * NSEQ + kt * 32) * DHEAD;
    #pragma unroll
    for (int j = 0; j < 16; j++) {
        int idx = t + j * 256;
        int r = idx >> 7, c = idx & 127;
        lds[r][c] = xt[r * DHEAD + c];
    }
    __syncthreads();
    // K fp8 slot: one 16B slot per thread (t = dcp*64 + hh*32 + r)
    {
        int dcp = t >> 6, hh = (t >> 5) & 1, r = t & 31;
        u32 w[4];
        #pragma unroll
        for (int b8 = 0; b8 < 2; b8++) {
            #pragma unroll
            for (int half = 0; half < 2; half++) {
                u32 acc = 0;
                #pragma unroll
                for (int i = 0; i < 4; i++) {
                    float f = lds[r][dcp * 32 + b8 * 16 + hh * 8 + half * 4 + i];
                    acc |= f2fp8(f) << (8 * i);
                }
                w[b8 * 2 + half] = acc;
            }
        }
        u32x4 wv = {w[0], w[1], w[2], w[3]};
        *(u32x4*)(void*)(Kp8 + (size_t)(b * NKT + kt) * KT8_B + t * 16) = wv;
    }
    // V bf16 slots: two per thread
    char* vout = Vp + (size_t)(b * NKT + kt) * VT_B;
    #pragma unroll
    for (int j = 0; j < 2; j++) {
        int slot = t + j * 256;
        int s = slot >> 8, db = (slot >> 6) & 3, hh = (slot >> 5) & 1, r = slot & 31;
        u16 tmp[8];
        #pragma unroll
        for (int i = 0; i < 8; i++) tmp[i] = f2bf(lds[s * 16 + hh * 8 + i][db * 32 + r]);
        *(bf16x8*)(void*)(vout + slot * 16) = *(const bf16x8*)(const void*)tmp;
    }
}

// ---------------- flash attention: fp8 QK^T, bf16 PV, 64 q-rows/wave ----------------
// 256 blocks x 4 waves (1 wave/SIMD); each wave = one kv-group, both 32-row q-tiles,
// K/V reused x2 from registers. Fixed-C softmax with C = fp8-exact diag score.
// K,Q fp8 (mfma_f32_32x32x16_fp8_fp8, i64 ops); V bf16. P via v_perm trunc + permlane.
__device__ __forceinline__ void load_k8(u32x4 (&k)[4], const char* p) {
    #pragma unroll
    for (int j = 0; j < 4; j++)
        k[j] = *(const u32x4*)(const void*)(p + j * 1024);
}

__device__ __forceinline__ void load_v(bf16x8 (&v)[8], const char* p) {
    #pragma unroll
    for (int db = 0; db < 4; db++) {
        v[2*db]   = *(const bf16x8*)(const void*)(p + db * 1024);          // s=0
        v[2*db+1] = *(const bf16x8*)(const void*)(p + 4096 + db * 1024);   // s=1
    }
}

__device__ __forceinline__ u32 packbf(float lo, float hi) {
    return __builtin_amdgcn_perm(__builtin_bit_cast(u32, hi),
                                 __builtin_bit_cast(u32, lo), 0x07060302u);
}

__device__ __forceinline__ void attn_tile(const u32x4 (&k8)[4], const bf16x8 (&vf)[8],
                                          const u32x4 (&q8)[4], f32x16 (&acc)[4],
                                          float diagL, float& lsum) {
    f32x16 zz = {0.f,0.f,0.f,0.f,0.f,0.f,0.f,0.f,0.f,0.f,0.f,0.f,0.f,0.f,0.f,0.f};
    // QK^T: 8 fp8 MFMAs (K=16 each), single accumulate chain
    f32x16 s = zz;
    #pragma unroll
    for (int j = 0; j < 4; j++) {
        i64 klo = (i64)k8[j][0] | ((i64)k8[j][1] << 32);
        i64 khi = (i64)k8[j][2] | ((i64)k8[j][3] << 32);
        i64 qlo = (i64)q8[j][0] | ((i64)q8[j][1] << 32);
        i64 qhi = (i64)q8[j][2] | ((i64)q8[j][3] << 32);
        s = __builtin_amdgcn_mfma_f32_32x32x16_fp8_fp8(klo, qlo, s, 0, 0, 0);
        s = __builtin_amdgcn_mfma_f32_32x32x16_fp8_fp8(khi, qhi, s, 0, 0, 0);
    }

    // fixed-shift softmax weights: p = 2^(s*log2e - diagL)
    float p[16];
    #pragma unroll
    for (int i = 0; i < 16; i++)
        p[i] = __builtin_amdgcn_exp2f(s[i] * LOG2E - diagL);
    float ss[8];
    #pragma unroll
    for (int i = 0; i < 8; i++) ss[i] = p[i] + p[i + 8];
    #pragma unroll
    for (int i = 0; i < 4; i++) ss[i] += ss[i + 4];
    lsum += (ss[0] + ss[1]) + (ss[2] + ss[3]);

    // P -> bf16 pairs (v_perm trunc) -> permlane32_swap -> PV B-fragments
    u32 c01   = packbf(p[0],  p[1]);
    u32 c23   = packbf(p[2],  p[3]);
    u32 c89   = packbf(p[4],  p[5]);
    u32 c1011 = packbf(p[6],  p[7]);
    u32 cA    = packbf(p[8],  p[9]);
    u32 cB    = packbf(p[10], p[11]);
    u32 cC    = packbf(p[12], p[13]);
    u32 cD    = packbf(p[14], p[15]);
    auto sA = __builtin_amdgcn_permlane32_swap(c01, c89,   false, false);
    auto sB = __builtin_amdgcn_permlane32_swap(c23, c1011, false, false);
    auto sC = __builtin_amdgcn_permlane32_swap(cA, cC,     false, false);
    auto sD = __builtin_amdgcn_permlane32_swap(cB, cD,     false, false);
    bf16x8 pb0 = __builtin_bit_cast(bf16x8, (u32x4){sA[0], sB[0], sA[1], sB[1]});
    bf16x8 pb1 = __builtin_bit_cast(bf16x8, (u32x4){sC[0], sD[0], sC[1], sD[1]});

    // PV: out^T += V^T . P^T, 4 d-blocks x 2 k-steps (bf16)
    #pragma unroll
    for (int db = 0; db < 4; db++) {
        acc[db] = __builtin_amdgcn_mfma_f32_32x32x16_bf16(vf[2*db],     pb0, acc[db], 0, 0, 0);
        acc[db] = __builtin_amdgcn_mfma_f32_32x32x16_bf16(vf[2*db + 1], pb1, acc[db], 0, 0, 0);
    }
}

__global__ __launch_bounds__(256, 1) void attn_kernel(const char* __restrict__ Kp8,
                                                      const char* __restrict__ Vp,
                                                      float* __restrict__ out) {
    __shared__ float Obuf[64 * OROW];          // 34.8 KB epilogue combine buffer
    __shared__ float Lx[GROUPS][64];

    int bid = blockIdx.x;            // 256 blocks, 1/CU (4 waves = 1/SIMD)
    int xcd = bid & 7, pos = bid >> 3;
    int b    = xcd >> 1;             // 2 XCDs per batch -> batch (1.5MB packed) L2-resident
    int qblk = pos + ((xcd & 1) << 5);

    int t = threadIdx.x;
    int w = t >> 6, l = t & 63;
    int grp = w;                     // each wave is one kv-group, owns all 64 q-rows
    int r  = l & 31;                 // lane row (m/n index)
    int hh = l >> 5;                 // k-half

    const char* Kpb = Kp8 + (size_t)b * NKT * KT8_B + (size_t)l * 16;
    const char* Vpb = Vp  + (size_t)b * NKT * VT_B  + (size_t)l * 16;

    // Q fragments for both q-tiles (fp8, same packing as K)
    u32x4 q0[4], q1[4];
    load_k8(q0, Kpb + (size_t)(qblk * 2)     * KT8_B);
    load_k8(q1, Kpb + (size_t)(qblk * 2 + 1) * KT8_B);

    // diag shift C = fp8-exact ||q||^2 (decode-square-sum own half + cross-half add)
    float dsq0 = 0.f, dsq1 = 0.f;
    #pragma unroll
    for (int j = 0; j < 4; j++) {
        #pragma unroll
        for (int wv = 0; wv < 4; wv++) {
            u32 w0 = q0[j][wv], w1 = q1[j][wv];
            #pragma unroll
            for (int by = 0; by < 4; by++) {
                float v0 = dfp8(w0 >> (8 * by));
                float v1 = dfp8(w1 >> (8 * by));
                dsq0 += v0 * v0;
                dsq1 += v1 * v1;
            }
        }
    }
    dsq0 += __shfl_xor(dsq0, 32);
    dsq1 += __shfl_xor(dsq1, 32);
    float diagL0 = dsq0 * LOG2E;
    float diagL1 = dsq1 * LOG2E;

    f32x16 zz = {0.f,0.f,0.f,0.f,0.f,0.f,0.f,0.f,0.f,0.f,0.f,0.f,0.f,0.f,0.f,0.f};
    f32x16 acc0[4], acc1[4];         // out^T: d = db*32+(reg&3)+8*(reg>>2)+4*hh, q = qt*32+r
    #pragma unroll
    for (int i = 0; i < 4; i++) { acc0[i] = zz; acc1[i] = zz; }
    float lsum0 = 0.f, lsum1 = 0.f;

    int kt0 = grp * NITER;           // this group's 32 tiles
    u32x4 kA[4], kB[4];
    bf16x8 vA[8], vB[8];
    load_k8(kA, Kpb + (size_t)kt0 * KT8_B);
    load_v(vA, Vpb + (size_t)kt0 * VT_B);
    for (int it = 0; it < NITER; it += 2) {
        int kt = kt0 + it;
        load_k8(kB, Kpb + (size_t)(kt + 1) * KT8_B);          // prefetch K,V tile it+1
        load_v(vB, Vpb + (size_t)(kt + 1) * VT_B);
        attn_tile(kA, vA, q0, acc0, diagL0, lsum0);           // K/V reused for both q-tiles
        attn_tile(kA, vA, q1, acc1, diagL1, lsum1);
        if (it + 2 < NITER) {
            load_k8(kA, Kpb + (size_t)(kt + 2) * KT8_B);      // prefetch K,V tile it+2
            load_v(vA, Vpb + (size_t)(kt + 2) * VT_B);
        }
        attn_tile(kB, vB, q0, acc0, diagL0, lsum0);
        attn_tile(kB, vB, q1, acc1, diagL1, lsum1);
    }

    // ---- combine 4 kv-groups (shared shift per row -> plain sums) ----
    lsum0 += __shfl_xor(lsum0, 32);
    lsum1 += __shfl_xor(lsum1, 32);
    if (l < 32) { Lx[grp][r] = lsum0; Lx[grp][32 + r] = lsum1; }
    __syncthreads();

    #pragma unroll
    for (int j = 0; j < GROUPS; j++) {
        if (grp == j) {
            #pragma unroll
            for (int db = 0; db < 4; db++) {
                #pragma unroll
                for (int rq = 0; rq < 4; rq++) {
                    int d0 = db * 32 + rq * 8 + hh * 4;
                    float* dst0 = Obuf + r * OROW + d0;
                    float* dst1 = Obuf + (32 + r) * OROW + d0;
                    f32x4 v0 = { acc0[db][rq*4+0], acc0[db][rq*4+1], acc0[db][rq*4+2], acc0[db][rq*4+3] };
                    f32x4 v1 = { acc1[db][rq*4+0], acc1[db][rq*4+1], acc1[db][rq*4+2], acc1[db][rq*4+3] };
                    if (j > 0) {
                        v0 += *(const f32x4*)(const void*)dst0;
                        v1 += *(const f32x4*)(const void*)dst1;
                    }
                    *(f32x4*)(void*)dst0 = v0;
                    *(f32x4*)(void*)dst1 = v1;
                }
            }
        }
        __syncthreads();
    }

    // coalesced final store: thread t -> row q2 = t>>2, 32 floats at (t&3)*32
    int q2 = t >> 2;
    int c0 = (t & 3) * 32;
    float lt = Lx[0][q2] + Lx[1][q2] + Lx[2][q2] + Lx[3][q2];
    float inv = 1.0f / lt;
    const float* srow = Obuf + q2 * OROW + c0;
    float* orow = out + ((size_t)b * NSEQ + (size_t)qblk * 64 + q2) * DHEAD + c0;
    #pragma unroll
    for (int k = 0; k < 8; k++) {
        f32x4 v = *(const f32x4*)(const void*)(srow + k * 4);
        v *= inv;
        *(f32x4*)(void*)(orow + k * 4) = v;
    }
}

extern "C" void kernel_launch(void* const* d_in, const int* in_sizes, int n_in,
                              void* d_out, int out_size, void* d_ws, size_t ws_size,
                              hipStream_t stream) {
    (void)in_sizes; (void)n_in; (void)out_size; (void)ws_size;
    const float* x = (const float*)d_in[0];
    float* out = (float*)d_out;
    char* Kp8 = (char*)d_ws;                                   // 2 MB fp8 K/Q fragments
    char* Vp  = Kp8 + (size_t)BATCH * NKT * KT8_B;             // 4 MB bf16 V^T fragments
    prep_kernel<<<BATCH * NKT, 256, 0, stream>>>(x, Kp8, Vp);
    attn_kernel<<<BATCH * (NSEQ / 64), 256, 0, stream>>>(Kp8, Vp, out);
}